// Round 2
// baseline (470.986 us; speedup 1.0000x reference)
//
#include <hip/hip_runtime.h>
#include <hip/hip_bf16.h>

// NeighborConsistencyLoss: loss = mean_s(1 - mean_k cos(z[c_s], z[knn[c_s,k]]))
//   z:[N,512] f32, knn:[N,32] i32, samp:[S] i32 -> scalar f32.
// Memory-bound gather (~66 MB HBM). R1 restructure: one WAVE per (sample,
// neighbor) pair -> grid = S*8 blocks x 256 thr (4 waves), 8x the wave count
// of R0 for memory-level parallelism. Each wave issues its 4 float4 gather
// loads (2KB center + 2KB neighbor row) up front, then runs three parallel
// 6-step butterfly reductions (cn, dp, nn). Center rows (2 MB total) are
// L1/L2-resident across their 32 re-reads, so HBM traffic stays ~66 MB.

#define DDIM 512
#define KNN 32
#define EPSV 1e-8f

__global__ __launch_bounds__(256) void ncl_pair_kernel(
    const float* __restrict__ z,
    const int* __restrict__ knn,
    const int* __restrict__ samp,
    float* __restrict__ block_sums) {
    const int b    = blockIdx.x;
    const int s    = b >> 3;        // sample index
    const int g    = b & 7;         // neighbor group (0..7)
    const int lane = threadIdx.x & 63;
    const int wave = threadIdx.x >> 6;
    const int k    = g * 4 + wave;  // this wave's neighbor (0..31)

    const int cidx = samp[s];                          // block-uniform
    const int nidx = knn[(size_t)cidx * KNN + k];      // wave-uniform

    const float4* __restrict__ crow = (const float4*)(z + (size_t)cidx * DDIM);
    const float4* __restrict__ nrow = (const float4*)(z + (size_t)nidx * DDIM);
    // All four gather loads issued before any use (independent, 4KB in flight).
    const float4 c0 = crow[lane];
    const float4 c1 = crow[64 + lane];
    const float4 n0 = nrow[lane];
    const float4 n1 = nrow[64 + lane];

    float cn = c0.x*c0.x; float dp = c0.x*n0.x; float nn = n0.x*n0.x;
    cn = fmaf(c0.y, c0.y, cn); dp = fmaf(c0.y, n0.y, dp); nn = fmaf(n0.y, n0.y, nn);
    cn = fmaf(c0.z, c0.z, cn); dp = fmaf(c0.z, n0.z, dp); nn = fmaf(n0.z, n0.z, nn);
    cn = fmaf(c0.w, c0.w, cn); dp = fmaf(c0.w, n0.w, dp); nn = fmaf(n0.w, n0.w, nn);
    cn = fmaf(c1.x, c1.x, cn); dp = fmaf(c1.x, n1.x, dp); nn = fmaf(n1.x, n1.x, nn);
    cn = fmaf(c1.y, c1.y, cn); dp = fmaf(c1.y, n1.y, dp); nn = fmaf(n1.y, n1.y, nn);
    cn = fmaf(c1.z, c1.z, cn); dp = fmaf(c1.z, n1.z, dp); nn = fmaf(n1.z, n1.z, nn);
    cn = fmaf(c1.w, c1.w, cn); dp = fmaf(c1.w, n1.w, dp); nn = fmaf(n1.w, n1.w, nn);

    // Three independent butterflies — chains overlap, latency ~= one chain.
    #pragma unroll
    for (int off = 32; off; off >>= 1) {
        cn += __shfl_xor(cn, off, 64);
        dp += __shfl_xor(dp, off, 64);
        nn += __shfl_xor(nn, off, 64);
    }

    __shared__ float red[4];
    if (lane == 0) {
        const float denom = fmaxf(sqrtf(cn) * sqrtf(nn), EPSV);
        red[wave] = dp / denom;
    }
    __syncthreads();
    if (threadIdx.x == 0)
        block_sums[b] = red[0] + red[1] + red[2] + red[3];
}

__global__ __launch_bounds__(256) void ncl_finalize_kernel(
    const float* __restrict__ block_sums, float* __restrict__ out, int nblocks, float inv_sk) {
    __shared__ float red[256];
    float acc = 0.0f;
    for (int i = threadIdx.x; i < nblocks; i += 256) acc += block_sums[i];
    red[threadIdx.x] = acc;
    __syncthreads();
    #pragma unroll
    for (int off = 128; off; off >>= 1) {
        if (threadIdx.x < off) red[threadIdx.x] += red[threadIdx.x + off];
        __syncthreads();
    }
    if (threadIdx.x == 0)
        out[0] = 1.0f - red[0] * inv_sk;
}

extern "C" void kernel_launch(void* const* d_in, const int* in_sizes, int n_in,
                              void* d_out, int out_size, void* d_ws, size_t ws_size,
                              hipStream_t stream) {
    const float* z    = (const float*)d_in[0];
    const int*   knn  = (const int*)d_in[1];
    const int*   samp = (const int*)d_in[2];
    const int    S    = in_sizes[2];
    const int    nblocks = S * 8;   // one wave per (s,k); 4 waves per block

    float* block_sums = (float*)d_ws;  // nblocks floats of scratch
    float* out        = (float*)d_out;

    ncl_pair_kernel<<<nblocks, 256, 0, stream>>>(z, knn, samp, block_sums);
    ncl_finalize_kernel<<<1, 256, 0, stream>>>(block_sums, out, nblocks,
                                               1.0f / ((float)S * (float)KNN));
}

// Round 3
// 466.686 us; speedup vs baseline: 1.0092x; 1.0092x over previous
//
#include <hip/hip_runtime.h>
#include <hip/hip_bf16.h>

// NeighborConsistencyLoss: loss = mean_s(1 - mean_k cos(z[c_s], z[knn[c_s,k]]))
//   z:[N,512] f32, knn:[N,32] i32, samp:[S] i32 -> scalar f32.
// R2: MLP-maximized gather. One wave per (sample, 4 neighbors):
//   - center row loaded once per wave, reused for 4 dot products
//   - all 10 float4 gather loads issued before any use (10 KB in flight/wave)
//   - 9 independent 6-step butterflies (cn + 4x{dp,nn}) overlap in the pipe
// Grid = S*2 = 2000 blocks x 4 waves. HBM floor ~62 MB unique rows ~= 10 us.

#define DDIM 512
#define KNN 32
#define EPSV 1e-8f

__global__ __launch_bounds__(256) void ncl_pair_kernel(
    const float* __restrict__ z,
    const int* __restrict__ knn,
    const int* __restrict__ samp,
    float* __restrict__ block_sums) {
    const int b    = blockIdx.x;
    const int s    = b >> 1;         // sample index
    const int h    = b & 1;          // which half of the 32 neighbors
    const int lane = threadIdx.x & 63;
    const int wave = threadIdx.x >> 6;
    const int kbase = h * 16 + wave * 4;   // this wave's 4 neighbors

    const int cidx = samp[s];                            // block-uniform
    const int* __restrict__ krow = knn + (size_t)cidx * KNN + kbase;
    const int i0 = krow[0], i1 = krow[1], i2 = krow[2], i3 = krow[3];

    const float4* __restrict__ crow = (const float4*)(z + (size_t)cidx * DDIM);
    const float4* __restrict__ r0 = (const float4*)(z + (size_t)i0 * DDIM);
    const float4* __restrict__ r1 = (const float4*)(z + (size_t)i1 * DDIM);
    const float4* __restrict__ r2 = (const float4*)(z + (size_t)i2 * DDIM);
    const float4* __restrict__ r3 = (const float4*)(z + (size_t)i3 * DDIM);

    // Issue every gather load before any use: 10 x 1KB-per-wave loads in flight.
    const float4 c0 = crow[lane];
    const float4 c1 = crow[64 + lane];
    const float4 a0 = r0[lane], a1 = r0[64 + lane];
    const float4 b0 = r1[lane], b1 = r1[64 + lane];
    const float4 d0 = r2[lane], d1 = r2[64 + lane];
    const float4 e0 = r3[lane], e1 = r3[64 + lane];

    float cn  = c0.x*c0.x;
    float dpa = c0.x*a0.x, nna = a0.x*a0.x;
    float dpb = c0.x*b0.x, nnb = b0.x*b0.x;
    float dpd = c0.x*d0.x, nnd = d0.x*d0.x;
    float dpe = c0.x*e0.x, nne = e0.x*e0.x;
#define ACC(cx, ax, bx, dx, ex)                                        \
    cn  = fmaf(cx, cx, cn);                                            \
    dpa = fmaf(cx, ax, dpa); nna = fmaf(ax, ax, nna);                  \
    dpb = fmaf(cx, bx, dpb); nnb = fmaf(bx, bx, nnb);                  \
    dpd = fmaf(cx, dx, dpd); nnd = fmaf(dx, dx, nnd);                  \
    dpe = fmaf(cx, ex, dpe); nne = fmaf(ex, ex, nne);
    ACC(c0.y, a0.y, b0.y, d0.y, e0.y)
    ACC(c0.z, a0.z, b0.z, d0.z, e0.z)
    ACC(c0.w, a0.w, b0.w, d0.w, e0.w)
    ACC(c1.x, a1.x, b1.x, d1.x, e1.x)
    ACC(c1.y, a1.y, b1.y, d1.y, e1.y)
    ACC(c1.z, a1.z, b1.z, d1.z, e1.z)
    ACC(c1.w, a1.w, b1.w, d1.w, e1.w)
#undef ACC

    // 9 independent butterflies — per-step ops are mutually independent.
    #pragma unroll
    for (int off = 32; off; off >>= 1) {
        cn  += __shfl_xor(cn,  off, 64);
        dpa += __shfl_xor(dpa, off, 64);
        nna += __shfl_xor(nna, off, 64);
        dpb += __shfl_xor(dpb, off, 64);
        nnb += __shfl_xor(nnb, off, 64);
        dpd += __shfl_xor(dpd, off, 64);
        nnd += __shfl_xor(nnd, off, 64);
        dpe += __shfl_xor(dpe, off, 64);
        nne += __shfl_xor(nne, off, 64);
    }

    __shared__ float red[4];
    if (lane == 0) {
        const float cnorm = sqrtf(cn);
        float w = dpa / fmaxf(cnorm * sqrtf(nna), EPSV);
        w      += dpb / fmaxf(cnorm * sqrtf(nnb), EPSV);
        w      += dpd / fmaxf(cnorm * sqrtf(nnd), EPSV);
        w      += dpe / fmaxf(cnorm * sqrtf(nne), EPSV);
        red[wave] = w;
    }
    __syncthreads();
    if (threadIdx.x == 0)
        block_sums[b] = red[0] + red[1] + red[2] + red[3];
}

__global__ __launch_bounds__(256) void ncl_finalize_kernel(
    const float* __restrict__ block_sums, float* __restrict__ out, int nblocks, float inv_sk) {
    __shared__ float red[256];
    float acc = 0.0f;
    for (int i = threadIdx.x; i < nblocks; i += 256) acc += block_sums[i];
    red[threadIdx.x] = acc;
    __syncthreads();
    #pragma unroll
    for (int off = 128; off; off >>= 1) {
        if (threadIdx.x < off) red[threadIdx.x] += red[threadIdx.x + off];
        __syncthreads();
    }
    if (threadIdx.x == 0)
        out[0] = 1.0f - red[0] * inv_sk;
}

extern "C" void kernel_launch(void* const* d_in, const int* in_sizes, int n_in,
                              void* d_out, int out_size, void* d_ws, size_t ws_size,
                              hipStream_t stream) {
    const float* z    = (const float*)d_in[0];
    const int*   knn  = (const int*)d_in[1];
    const int*   samp = (const int*)d_in[2];
    const int    S    = in_sizes[2];
    const int    nblocks = S * 2;   // one wave per (s, 4 neighbors)

    float* block_sums = (float*)d_ws;  // nblocks floats of scratch
    float* out        = (float*)d_out;

    ncl_pair_kernel<<<nblocks, 256, 0, stream>>>(z, knn, samp, block_sums);
    ncl_finalize_kernel<<<1, 256, 0, stream>>>(block_sums, out, nblocks,
                                               1.0f / ((float)S * (float)KNN));
}